// Round 1
// baseline (80.573 us; speedup 1.0000x reference)
//
#include <hip/hip_runtime.h>

// upfirdn2d: up=1, down=2, 4x4 kernel, pad=(1,1)
// x: (8,128,256,256) f32 ; kernel: (4,4) f32 (already normalized)
// out: (8,128,128,128) f32
//
// out[n,c,oh,ow] = sum_{i,j in 0..3} x[n,c, 2*oh+i-1, 2*ow+j-1] * kflip[i][j]
// with zero padding outside [0,256).

#define XH 256
#define XW 256
#define OHH 128
#define OWW 128

__global__ __launch_bounds__(256) void downfir2_kernel(
    const float* __restrict__ x, const float* __restrict__ k,
    float* __restrict__ out) {
  const int img = blockIdx.x;      // n*C + c  (0..1023)
  const int tx  = threadIdx.x;     // 0..15 -> 8 output cols each
  const int ty  = threadIdx.y;     // 0..15 -> 8 output rows each

  // flipped kernel weights (true convolution)
  float w[4][4];
#pragma unroll
  for (int i = 0; i < 4; ++i)
#pragma unroll
    for (int j = 0; j < 4; ++j)
      w[i][j] = k[(3 - i) * 4 + (3 - j)];

  const float* xim = x + (size_t)img * (XH * XW);
  float* oim = out + (size_t)img * (OHH * OWW);

  float acc[8][8];
#pragma unroll
  for (int r = 0; r < 8; ++r)
#pragma unroll
    for (int q = 0; q < 8; ++q) acc[r][q] = 0.f;

  // This thread's outputs: oh = 8*ty + r, ow = 8*tx + q  (r,q in 0..7)
  // Needed input rows: ih = 16*ty - 1 + s, s in [0,18)
  // Needed input cols: iw in [16*tx - 1, 16*tx + 16] -> load 24 cols
  // starting at 16*tx - 4 via 6 aligned float4 (clamped base, fixed up).
  const int rowbase = 16 * ty - 1;
  const int colbase = 16 * tx - 4;

#pragma unroll
  for (int s = 0; s < 18; ++s) {
    const int ih = rowbase + s;
    if (ih < 0 || ih >= XH) continue;  // zero pad rows (only edge waves)
    const float* rp = xim + (size_t)ih * XW;

    float row[24];
#pragma unroll
    for (int b = 0; b < 6; ++b) {
      int iw0 = colbase + 4 * b;
      iw0 = iw0 < 0 ? 0 : (iw0 > XW - 4 ? XW - 4 : iw0);  // safe, aligned
      const float4 v = *reinterpret_cast<const float4*>(rp + iw0);
      row[4 * b + 0] = v.x;
      row[4 * b + 1] = v.y;
      row[4 * b + 2] = v.z;
      row[4 * b + 3] = v.w;
    }
    // zero-pad fixups: lc = (iw - colbase); iw=-1 -> lc=3 ; iw=256 -> lc=20
    if (tx == 0)  row[3]  = 0.f;
    if (tx == 15) row[20] = 0.f;

    // row s contributes to output rows r where i = s - 2r in [0,3]
#pragma unroll
    for (int r = 0; r < 8; ++r) {
      const int i = s - 2 * r;
      if (i < 0 || i > 3) continue;  // compile-time after unroll
#pragma unroll
      for (int q = 0; q < 8; ++q) {
        // iw = 2*(8tx+q) + j - 1 -> lc = 2q + j + 3
        float a = acc[r][q];
        a = fmaf(w[i][0], row[2 * q + 3], a);
        a = fmaf(w[i][1], row[2 * q + 4], a);
        a = fmaf(w[i][2], row[2 * q + 5], a);
        acc[r][q] = fmaf(w[i][3], row[2 * q + 6], a);
      }
    }
  }

#pragma unroll
  for (int r = 0; r < 8; ++r) {
    float* op = oim + (size_t)(8 * ty + r) * OWW + 8 * tx;
    float4 v0 = make_float4(acc[r][0], acc[r][1], acc[r][2], acc[r][3]);
    float4 v1 = make_float4(acc[r][4], acc[r][5], acc[r][6], acc[r][7]);
    *reinterpret_cast<float4*>(op) = v0;
    *reinterpret_cast<float4*>(op + 4) = v1;
  }
}

extern "C" void kernel_launch(void* const* d_in, const int* in_sizes, int n_in,
                              void* d_out, int out_size, void* d_ws, size_t ws_size,
                              hipStream_t stream) {
  const float* x = (const float*)d_in[0];
  const float* k = (const float*)d_in[1];
  float* out = (float*)d_out;

  // one block per (n,c) image: 8*128 = 1024 blocks, 256 threads each
  dim3 grid(8 * 128);
  dim3 block(16, 16);
  downfir2_kernel<<<grid, block, 0, stream>>>(x, k, out);
}

// Round 2
// 71.717 us; speedup vs baseline: 1.1235x; 1.1235x over previous
//
#include <hip/hip_runtime.h>

// upfirdn2d: up=1, down=2, 4x4 kernel, pad=(1,1)
// x: (8,128,256,256) f32 ; kernel: (4,4) f32 ; out: (8,128,128,128) f32
//
// out[n,c,oh,ow] = sum_{i,j} x[n,c, 2*oh+i-1, 2*ow+j-1] * kflip[i][j]
//
// Structure: one wave = one full-width row slab. Each input row is loaded by
// the wave as 64 aligned float4 lanes = 256 floats = whole row, one fully
// coalesced 1 KiB instruction. Column halo (iw = 4l-1 and 4l+4) comes from
// neighbor lanes via __shfl. Each lane produces output cols {2l, 2l+1} for
// 8 output rows (16 outputs, acc = 16 VGPRs).

#define XH 256
#define XW 256
#define OH 128
#define OW 128

__global__ __launch_bounds__(256) void downfir2_kernel(
    const float* __restrict__ x, const float* __restrict__ k,
    float* __restrict__ out) {
  const int lane = threadIdx.x & 63;
  const int wv   = threadIdx.x >> 6;   // 0..3
  const int bid  = blockIdx.x;
  const int img  = bid >> 2;           // 0..1023  (n*C + c)
  const int slab = bid & 3;            // 0..3 -> 32 output rows each
  const int oh0  = slab * 32 + wv * 8; // this wave's first output row

  // flipped kernel weights; k is uniform + constant offsets -> scalar loads
  float w[4][4];
#pragma unroll
  for (int i = 0; i < 4; ++i)
#pragma unroll
    for (int j = 0; j < 4; ++j) w[i][j] = k[(3 - i) * 4 + (3 - j)];

  const float* xim = x + (size_t)img * (XH * XW);
  float* oim = out + (size_t)img * (OH * OW);

  float acc[8][2];
#pragma unroll
  for (int r = 0; r < 8; ++r) { acc[r][0] = 0.f; acc[r][1] = 0.f; }

  // input rows needed: ih in [2*oh0 - 1, 2*oh0 + 16]  (18 rows)
  const int rowbase = 2 * oh0 - 1;
#pragma unroll
  for (int s = 0; s < 18; ++s) {
    const int ih = rowbase + s;        // wave-uniform
    float4 v = make_float4(0.f, 0.f, 0.f, 0.f);
    if (ih >= 0 && ih < XH)            // zero-pad rows (uniform branch)
      v = *reinterpret_cast<const float4*>(xim + (size_t)ih * XW + 4 * lane);

    // column halo: iw = 4l-1 from lane l-1 (.w), iw = 4l+4 from lane l+1 (.x)
    float left  = __shfl_up(v.w, 1);
    float right = __shfl_down(v.x, 1);
    if (lane == 0)  left  = 0.f;       // iw = -1   -> pad
    if (lane == 63) right = 0.f;       // iw = 256  -> pad

    // row s contributes to output row r iff i = s - 2r in [0,3] (2 r's per s)
#pragma unroll
    for (int r = 0; r < 8; ++r) {
      const int i = s - 2 * r;
      if (i < 0 || i > 3) continue;    // compile-time after unroll
      float a0 = acc[r][0], a1 = acc[r][1];
      // ow = 2l   : iw = 4l-1 .. 4l+2 = {left, v.x, v.y, v.z}
      a0 = fmaf(w[i][0], left, a0);
      a0 = fmaf(w[i][1], v.x, a0);
      a0 = fmaf(w[i][2], v.y, a0);
      a0 = fmaf(w[i][3], v.z, a0);
      // ow = 2l+1 : iw = 4l+1 .. 4l+4 = {v.y, v.z, v.w, right}
      a1 = fmaf(w[i][0], v.y, a1);
      a1 = fmaf(w[i][1], v.z, a1);
      a1 = fmaf(w[i][2], v.w, a1);
      a1 = fmaf(w[i][3], right, a1);
      acc[r][0] = a0; acc[r][1] = a1;
    }
  }

  // store: wave writes 8 full output rows, 8 B/lane contiguous (512 B/instr)
#pragma unroll
  for (int r = 0; r < 8; ++r) {
    float2 o;
    o.x = acc[r][0];
    o.y = acc[r][1];
    *reinterpret_cast<float2*>(oim + (size_t)(oh0 + r) * OW + 2 * lane) = o;
  }
}

extern "C" void kernel_launch(void* const* d_in, const int* in_sizes, int n_in,
                              void* d_out, int out_size, void* d_ws, size_t ws_size,
                              hipStream_t stream) {
  const float* x = (const float*)d_in[0];
  const float* k = (const float*)d_in[1];
  float* out = (float*)d_out;

  // 1024 images x 4 slabs = 4096 blocks, 256 threads (4 waves) each
  dim3 grid(8 * 128 * 4);
  dim3 block(256);
  downfir2_kernel<<<grid, block, 0, stream>>>(x, k, out);
}